// Round 12
// baseline (481.635 us; speedup 1.0000x reference)
//
#include <hip/hip_runtime.h>
#include <math.h>

#define BATCH   65536
#define DIM     64
#define HID     128
#define SPLIT   32
#define NBINS   8
#define PDIM    25          // 3*NBINS+1
#define NLAYERS 6
#define R_MIN   (-5.0f)
#define R_MAX   (5.0f)
#define MIN_BIN   1.0e-4f
#define MIN_SLOPE 1.0e-4f
#define SOFF      0.54116666f   // log(exp(1-MIN_SLOPE)-1)

#define ROWSW 16      // rows per wave
#define WAVES 4
#define MBLK  64      // rows per block
#define NT    256
#define XPAD  68      // xf row stride (f32): bank-shifts rows, float4-aligned

#define N_W1  (HID*SPLIT)      // 4096
#define N_W2  (HID*HID)        // 16384
#define N_W4P (32*32*HID)      // 131072 (8 tb x 8 pq x 4 kt chunks of 512)
#define N_W4  (SPLIT*PDIM*HID) // 102400

typedef __attribute__((ext_vector_type(8))) short bf16x8;
typedef __attribute__((ext_vector_type(4))) float f32x4;

__device__ __forceinline__ short f2bf(float f) {
    unsigned u = __builtin_bit_cast(unsigned, f);
    unsigned r = u + 0x7FFFu + ((u >> 16) & 1u);   // RNE
    return (short)(r >> 16);
}

__device__ __forceinline__ unsigned pk2(float a, float b) {   // 2xf32 -> packed bf16 (RNE)
    unsigned r;
    asm("v_cvt_pk_bf16_f32 %0, %1, %2" : "=v"(r) : "v"(a), "v"(b));
    return r;
}

// act LDS layout: [group g = k>>2][row r][k&3] shorts, group stride 64 shorts.
__device__ __forceinline__ bf16x8 ldfrag(const short* base) {
    short4 lo = *reinterpret_cast<const short4*>(base);
    short4 hi = *reinterpret_cast<const short4*>(base + 64);
    bf16x8 a;
    a[0]=lo.x; a[1]=lo.y; a[2]=lo.z; a[3]=lo.w;
    a[4]=hi.x; a[5]=hi.y; a[6]=hi.z; a[7]=hi.w;
    return a;
}

// ---- weight conversion prologue (fragment packing, same as R5-R7) ----
__global__ void cvt_weights(const float* __restrict__ W1, const float* __restrict__ W2,
                            const float* __restrict__ W3, const float* __restrict__ W4,
                            const float* __restrict__ b4,
                            short* __restrict__ o1, short* __restrict__ o2,
                            short* __restrict__ o3, short* __restrict__ o4,
                            float* __restrict__ b4q) {
    const int stride = gridDim.x * blockDim.x;
    const int i0 = blockIdx.x * blockDim.x + threadIdx.x;
    for (int i = i0; i < NLAYERS*N_W1; i += stride) {
        const int L = i >> 12, rem = i & 4095;
        const int nt = rem >> 9, q = rem & 511;
        const int l = q >> 3, e = q & 7;
        o1[i] = f2bf(W1[L*N_W1 + (nt*16 + (l&15))*SPLIT + (l>>4)*8 + e]);
    }
    for (int i = i0; i < NLAYERS*N_W2; i += stride) {
        const int L = i >> 14, rem = i & 16383;
        const int c = rem >> 9, q = rem & 511;
        const int nt = c >> 2, kt = c & 3;
        const int l = q >> 3, e = q & 7;
        const int src = L*N_W2 + (nt*16 + (l&15))*HID + kt*32 + (l>>4)*8 + e;
        o2[i] = f2bf(W2[src]);
        o3[i] = f2bf(W3[src]);
    }
    for (int i = i0; i < NLAYERS*N_W4P; i += stride) {
        const int L = i >> 17, rem = i & (N_W4P - 1);
        const int c = rem >> 9, q = rem & 511;
        const int tb = c >> 5, pq = (c >> 2) & 7, kt = c & 3;
        const int l = q >> 3, e = q & 7;
        const int t = tb*4 + ((l & 15) >> 2);
        const int p = pq*4 + (l & 3);
        o4[i] = (p < PDIM)
              ? f2bf(W4[(size_t)L*N_W4 + (size_t)(t*PDIM + p)*HID + kt*32 + (l>>4)*8 + e])
              : (short)0;
    }
    for (int i = i0; i < NLAYERS*SPLIT*32; i += stride) {
        const int L = i >> 10, rem = i & 1023;
        const int t = rem >> 5, p = rem & 31;
        b4q[i] = (p < PDIM) ? b4[L*SPLIT*PDIM + t*PDIM + p] : 0.0f;
    }
}

// ALL 6 coupling layers fused. Each wave owns 16 rows end-to-end; the row
// state (64 f32 dims) lives in wave-private LDS xf for the whole flow.
// Global traffic: one coalesced read of x, one coalesced write of y, logdet.
__global__ __launch_bounds__(NT, 4) void flow_all(
    const float* __restrict__ xin, float* __restrict__ yout, float* __restrict__ logdet,
    const short* __restrict__ bW1, const float* __restrict__ b1a,
    const short* __restrict__ bW2, const float* __restrict__ b2a,
    const short* __restrict__ bW3, const float* __restrict__ b3a,
    const short* __restrict__ bW4, const float* __restrict__ b4qa,
    const int* __restrict__ mia, const int* __restrict__ tia)
{
    __shared__ short act[WAVES][32 * 64];         // per-wave bf16 act fragments
    __shared__ float xf[WAVES][ROWSW][XPAD];      // per-wave row state (f32)

    const int tid = threadIdx.x;
    const int wv  = tid >> 6;    // wave id
    const int l   = tid & 63;    // lane
    const int lr  = l & 15;      // row / col-in-tile
    const int lg  = l >> 4;      // 0..3
    const int rbase = blockIdx.x * MBLK + wv * ROWSW;

    short* const actw = &act[wv][0];
    float (* const xr)[XPAD] = xf[wv];

    // ---- load input rows, fully coalesced float4 ----
    #pragma unroll
    for (int i = 0; i < 4; ++i) {
        const int r = (l >> 4) + i * 4;
        const int d = (l & 15) * 4;
        const float4 v = *reinterpret_cast<const float4*>(xin + (size_t)(rbase + r) * DIM + d);
        *reinterpret_cast<float4*>(&xr[r][d]) = v;
    }

    float ldacc = 0.0f;

    #pragma unroll 1
    for (int L = 0; L < NLAYERS; ++L) {
        const short* w1 = bW1 + (size_t)L * N_W1;
        const short* w2 = bW2 + (size_t)L * N_W2;
        const short* w3 = bW3 + (size_t)L * N_W2;
        const short* w4 = bW4 + (size_t)L * N_W4P;
        const float* bb1 = b1a + L * HID;
        const float* bb2 = b2a + L * HID;
        const float* bb3 = b3a + L * HID;
        const float* bq  = b4qa + (size_t)L * SPLIT * 32;
        const int* mil = mia + L * SPLIT;
        const int* til = tia + L * SPLIT;

        // ---- gather masked half from row state -> act (bf16) ----
        {
            const int kcol = l & 31;
            const int mc = mil[kcol];
            const int r0 = l >> 5;                // 0 or 1
            #pragma unroll
            for (int it = 0; it < 8; ++it) {
                const int r = r0 + it * 2;
                actw[(kcol >> 2)*64 + r*4 + (kcol & 3)] = f2bf(xr[r][mc]);
            }
        }

        // ================= h1 = relu(W1 @ xm^T + b1)  [K=32] =================
        {
            const bf16x8 afr = ldfrag(&actw[(2*lg)*64 + lr*4]);
            f32x4 c[8];
            #pragma unroll
            for (int nt = 0; nt < 8; ++nt) {
                const float4 bv = *reinterpret_cast<const float4*>(bb1 + nt*16 + lg*4);
                c[nt] = (f32x4){bv.x, bv.y, bv.z, bv.w};
            }
            #pragma unroll
            for (int nt = 0; nt < 8; ++nt) {
                const bf16x8 wfr = *reinterpret_cast<const bf16x8*>(w1 + (size_t)nt*512 + l*8);
                c[nt] = __builtin_amdgcn_mfma_f32_16x16x32_bf16(wfr, afr, c[nt], 0, 0, 0);
            }
            #pragma unroll
            for (int nt = 0; nt < 8; ++nt) {
                const unsigned u0 = pk2(fmaxf(c[nt][0], 0.0f), fmaxf(c[nt][1], 0.0f));
                const unsigned u1 = pk2(fmaxf(c[nt][2], 0.0f), fmaxf(c[nt][3], 0.0f));
                *reinterpret_cast<uint2*>(&actw[(nt*4 + lg)*64 + lr*4]) = (uint2){u0, u1};
            }
        }

        // ================= h2 / h3  [K=128] =================
        #pragma unroll 1
        for (int ph = 0; ph < 2; ++ph) {
            const short* Wp = ph ? w3 : w2;
            const float* bp = ph ? bb3 : bb2;
            bf16x8 afr[4];
            #pragma unroll
            for (int kt = 0; kt < 4; ++kt)
                afr[kt] = ldfrag(&actw[(kt*8 + 2*lg)*64 + lr*4]);
            f32x4 c[8];
            #pragma unroll
            for (int nt = 0; nt < 8; ++nt) {
                const float4 bv = *reinterpret_cast<const float4*>(bp + nt*16 + lg*4);
                c[nt] = (f32x4){bv.x, bv.y, bv.z, bv.w};
            }
            #pragma unroll
            for (int kt = 0; kt < 4; ++kt)
                #pragma unroll
                for (int nt = 0; nt < 8; ++nt) {
                    const bf16x8 wfr = *reinterpret_cast<const bf16x8*>(Wp + (size_t)(nt*4 + kt)*512 + l*8);
                    c[nt] = __builtin_amdgcn_mfma_f32_16x16x32_bf16(wfr, afr[kt], c[nt], 0, 0, 0);
                }
            #pragma unroll
            for (int nt = 0; nt < 8; ++nt) {
                const unsigned u0 = pk2(fmaxf(c[nt][0], 0.0f), fmaxf(c[nt][1], 0.0f));
                const unsigned u1 = pk2(fmaxf(c[nt][2], 0.0f), fmaxf(c[nt][3], 0.0f));
                *reinterpret_cast<uint2*>(&actw[(nt*4 + lg)*64 + lr*4]) = (uint2){u0, u1};
            }
        }

        // ================= W4 params + RQS spline =================
        bf16x8 afr[4];
        #pragma unroll
        for (int kt = 0; kt < 4; ++kt)
            afr[kt] = ldfrag(&actw[(kt*8 + 2*lg)*64 + lr*4]);

        #pragma unroll 1
        for (int tb = 0; tb < 8; ++tb) {
            const int t = tb*4 + lg;           // this lane's t-dim
            f32x4 c[7];
            #pragma unroll
            for (int pq = 0; pq < 7; ++pq) {
                const float4 bv = *reinterpret_cast<const float4*>(bq + t*32 + pq*4);
                c[pq] = (f32x4){bv.x, bv.y, bv.z, bv.w};
            }
            #pragma unroll
            for (int kt = 0; kt < 4; ++kt)
                #pragma unroll
                for (int pq = 0; pq < 7; ++pq) {
                    const bf16x8 wfr = *reinterpret_cast<const bf16x8*>(
                        w4 + (size_t)((tb*8 + pq)*4 + kt)*512 + l*8);
                    c[pq] = __builtin_amdgcn_mfma_f32_16x16x32_bf16(wfr, afr[kt], c[pq], 0, 0, 0);
                }

            // lane holds the 28 params of (row = lr, t):  P(i) = c[i>>2][i&3]
#define P(i) c[(i)>>2][(i)&3]
            float wd[NBINS], hg[NBINS];
            float sw = 0.0f, sh = 0.0f;
            #pragma unroll
            for (int i = 0; i < NBINS; ++i) { wd[i] = __expf(P(i));         sw += wd[i]; }
            #pragma unroll
            for (int i = 0; i < NBINS; ++i) { hg[i] = __expf(P(NBINS + i)); sh += hg[i]; }
            const float scw = __fdividef((R_MAX - R_MIN) - NBINS * MIN_BIN, sw);
            const float sch = __fdividef((R_MAX - R_MIN) - NBINS * MIN_BIN, sh);
            #pragma unroll
            for (int i = 0; i < NBINS; ++i) { wd[i] = wd[i]*scw + MIN_BIN; hg[i] = hg[i]*sch + MIN_BIN; }

            const int tdim = til[t];
            const float x = xr[lr][tdim];

            // merged cumsum + bin select (last knot with x_pos <= x wins)
            float cx = R_MIN, cy = R_MIN;
            float x_k = R_MIN, y_k = R_MIN, wsel = wd[0], hsel = hg[0];
            float z0 = P(16), z1 = P(17);
            #pragma unroll
            for (int i = 1; i < NBINS; ++i) {
                cx += wd[i-1]; cy += hg[i-1];
                const bool tk = (cx <= x);
                x_k  = tk ? cx        : x_k;
                y_k  = tk ? cy        : y_k;
                wsel = tk ? wd[i]     : wsel;
                hsel = tk ? hg[i]     : hsel;
                z0   = tk ? P(16 + i) : z0;
                z1   = tk ? P(17 + i) : z1;
            }

            auto sp = [](float v) {
                const float z = v + SOFF;
                return ((z > 15.0f) ? z : __logf(1.0f + __expf(z))) + MIN_SLOPE;
            };
            const float d_k = sp(z0), d_k1 = sp(z1);
            const float sl0 = sp(P(16)), sl8 = sp(P(24));
#undef P

            const float invw = __fdividef(1.0f, wsel);
            float xi = (x - x_k) * invw;
            xi = fminf(fmaxf(xi, 0.0f), 1.0f);
            const float s    = hsel * invw;
            const float xi1m = 1.0f - xi;
            const float q    = xi * xi1m;
            const float num  = s * xi * xi + d_k * q;
            const float den  = s + (d_k1 + d_k - 2.0f * s) * q;
            const float invden = __fdividef(1.0f, den);
            const float y_sp = y_k + hsel * num * invden;
            const float deriv = s * s * (d_k1 * xi * xi + 2.0f * s * q + d_k * xi1m * xi1m)
                                * invden * invden;

            const bool below = x < R_MIN;
            const bool above = x > R_MAX;
            const float yv = below ? ((x - R_MIN) * sl0 + R_MIN)
                           : (above ? ((x - R_MAX) * sl8 + R_MAX) : y_sp);
            const float dv = below ? sl0 : (above ? sl8 : deriv);
            ldacc += __logf(dv);

            xr[lr][tdim] = yv;                 // update row state in LDS
        }
    }

    // ---- epilogue: coalesced float4 write of final rows + logdet ----
    #pragma unroll
    for (int i = 0; i < 4; ++i) {
        const int r = (l >> 4) + i * 4;
        const int d = (l & 15) * 4;
        *reinterpret_cast<float4*>(yout + (size_t)(rbase + r) * DIM + d) =
            *reinterpret_cast<const float4*>(&xr[r][d]);
    }
    ldacc += __shfl_xor(ldacc, 16, 64);
    ldacc += __shfl_xor(ldacc, 32, 64);
    if (l < 16) logdet[rbase + lr] = ldacc;
}

extern "C" void kernel_launch(void* const* d_in, const int* in_sizes, int n_in,
                              void* d_out, int out_size, void* d_ws, size_t ws_size,
                              hipStream_t stream) {
    const float* x  = (const float*)d_in[0];
    const float* W1 = (const float*)d_in[1];
    const float* b1 = (const float*)d_in[2];
    const float* W2 = (const float*)d_in[3];
    const float* b2 = (const float*)d_in[4];
    const float* W3 = (const float*)d_in[5];
    const float* b3 = (const float*)d_in[6];
    const float* W4 = (const float*)d_in[7];
    const float* b4 = (const float*)d_in[8];
    const int*   mi = (const int*)d_in[9];
    const int*   ti = (const int*)d_in[10];

    float* y      = (float*)d_out;
    float* logdet = y + (size_t)BATCH * DIM;

    short* bW1 = (short*)d_ws;
    short* bW2 = bW1 + NLAYERS * N_W1;
    short* bW3 = bW2 + NLAYERS * N_W2;
    short* bW4 = bW3 + NLAYERS * N_W2;
    float* b4q = (float*)(bW4 + (size_t)NLAYERS * N_W4P);

    cvt_weights<<<512, 256, 0, stream>>>(W1, W2, W3, W4, b4, bW1, bW2, bW3, bW4, b4q);

    dim3 grid(BATCH / MBLK), block(NT);
    flow_all<<<grid, block, 0, stream>>>(x, y, logdet,
        bW1, b1, bW2, b2, bW3, b3, bW4, b4q, mi, ti);
}

// Round 13
// 414.750 us; speedup vs baseline: 1.1613x; 1.1613x over previous
//
#include <hip/hip_runtime.h>
#include <math.h>

#define BATCH   65536
#define DIM     64
#define HID     128
#define SPLIT   32
#define NBINS   8
#define PDIM    25          // 3*NBINS+1
#define NLAYERS 6
#define R_MIN   (-5.0f)
#define R_MAX   (5.0f)
#define MIN_BIN   1.0e-4f
#define MIN_SLOPE 1.0e-4f
#define SOFF      0.54116666f   // log(exp(1-MIN_SLOPE)-1)

#define ROWSW 16      // rows per wave
#define WAVES 4
#define MBLK  64      // rows per block
#define NT    256

#define N_W1  (HID*SPLIT)      // 4096
#define N_W2  (HID*HID)        // 16384
#define N_W4P (32*32*HID)      // 131072 (8 tb x 8 pq x 4 kt chunks of 512)
#define N_W4  (SPLIT*PDIM*HID) // 102400

typedef __attribute__((ext_vector_type(8))) short bf16x8;
typedef __attribute__((ext_vector_type(4))) float f32x4;

__device__ __forceinline__ short f2bf(float f) {
    unsigned u = __builtin_bit_cast(unsigned, f);
    unsigned r = u + 0x7FFFu + ((u >> 16) & 1u);   // RNE
    return (short)(r >> 16);
}

__device__ __forceinline__ unsigned pk2(float a, float b) {   // 2xf32 -> packed bf16 (RNE)
    unsigned r;
    asm("v_cvt_pk_bf16_f32 %0, %1, %2" : "=v"(r) : "v"(a), "v"(b));
    return r;
}

// act LDS layout: [group g = k>>2][row r][k&3] shorts, group stride 64 shorts.
__device__ __forceinline__ bf16x8 ldfrag(const short* base) {
    short4 lo = *reinterpret_cast<const short4*>(base);
    short4 hi = *reinterpret_cast<const short4*>(base + 64);
    bf16x8 a;
    a[0]=lo.x; a[1]=lo.y; a[2]=lo.z; a[3]=lo.w;
    a[4]=hi.x; a[5]=hi.y; a[6]=hi.z; a[7]=hi.w;
    return a;
}

// full RQS spline for one (row,t): p[28] = {8 width-logits, 8 height-logits,
// 9 slope-logits + pad}; returns y, writes |dy/dx| to dv_out. Static idx only.
__device__ __forceinline__ float spline_eval(const float* p, float x, float& dv_out) {
    float wd[NBINS], hg[NBINS];
    float sw = 0.0f, sh = 0.0f;
    #pragma unroll
    for (int i = 0; i < NBINS; ++i) { wd[i] = __expf(p[i]);         sw += wd[i]; }
    #pragma unroll
    for (int i = 0; i < NBINS; ++i) { hg[i] = __expf(p[NBINS + i]); sh += hg[i]; }
    const float scw = __fdividef((R_MAX - R_MIN) - NBINS * MIN_BIN, sw);
    const float sch = __fdividef((R_MAX - R_MIN) - NBINS * MIN_BIN, sh);
    #pragma unroll
    for (int i = 0; i < NBINS; ++i) { wd[i] = wd[i]*scw + MIN_BIN; hg[i] = hg[i]*sch + MIN_BIN; }

    // merged cumsum + bin select (last knot with x_pos <= x wins)
    float cx = R_MIN, cy = R_MIN;
    float x_k = R_MIN, y_k = R_MIN, wsel = wd[0], hsel = hg[0];
    float z0 = p[16], z1 = p[17];
    #pragma unroll
    for (int i = 1; i < NBINS; ++i) {
        cx += wd[i-1]; cy += hg[i-1];
        const bool tk = (cx <= x);
        x_k  = tk ? cx        : x_k;
        y_k  = tk ? cy        : y_k;
        wsel = tk ? wd[i]     : wsel;
        hsel = tk ? hg[i]     : hsel;
        z0   = tk ? p[16 + i] : z0;
        z1   = tk ? p[17 + i] : z1;
    }

    auto sp = [](float v) {
        const float z = v + SOFF;
        return ((z > 15.0f) ? z : __logf(1.0f + __expf(z))) + MIN_SLOPE;
    };
    const float d_k = sp(z0), d_k1 = sp(z1);
    const float sl0 = sp(p[16]), sl8 = sp(p[24]);

    const float invw = __fdividef(1.0f, wsel);
    float xi = (x - x_k) * invw;
    xi = fminf(fmaxf(xi, 0.0f), 1.0f);
    const float s    = hsel * invw;
    const float xi1m = 1.0f - xi;
    const float q    = xi * xi1m;
    const float num  = s * xi * xi + d_k * q;
    const float den  = s + (d_k1 + d_k - 2.0f * s) * q;
    const float invden = __fdividef(1.0f, den);
    const float y_sp = y_k + hsel * num * invden;
    const float deriv = s * s * (d_k1 * xi * xi + 2.0f * s * q + d_k * xi1m * xi1m)
                        * invden * invden;

    const bool below = x < R_MIN;
    const bool above = x > R_MAX;
    dv_out = below ? sl0 : (above ? sl8 : deriv);
    return below ? ((x - R_MIN) * sl0 + R_MIN)
         : (above ? ((x - R_MAX) * sl8 + R_MAX) : y_sp);
}

// ---- weight conversion prologue (fragment packing, same as R5-R7) ----
__global__ void cvt_weights(const float* __restrict__ W1, const float* __restrict__ W2,
                            const float* __restrict__ W3, const float* __restrict__ W4,
                            const float* __restrict__ b4,
                            short* __restrict__ o1, short* __restrict__ o2,
                            short* __restrict__ o3, short* __restrict__ o4,
                            float* __restrict__ b4q) {
    const int stride = gridDim.x * blockDim.x;
    const int i0 = blockIdx.x * blockDim.x + threadIdx.x;
    for (int i = i0; i < NLAYERS*N_W1; i += stride) {
        const int L = i >> 12, rem = i & 4095;
        const int nt = rem >> 9, q = rem & 511;
        const int l = q >> 3, e = q & 7;
        o1[i] = f2bf(W1[L*N_W1 + (nt*16 + (l&15))*SPLIT + (l>>4)*8 + e]);
    }
    for (int i = i0; i < NLAYERS*N_W2; i += stride) {
        const int L = i >> 14, rem = i & 16383;
        const int c = rem >> 9, q = rem & 511;
        const int nt = c >> 2, kt = c & 3;
        const int l = q >> 3, e = q & 7;
        const int src = L*N_W2 + (nt*16 + (l&15))*HID + kt*32 + (l>>4)*8 + e;
        o2[i] = f2bf(W2[src]);
        o3[i] = f2bf(W3[src]);
    }
    for (int i = i0; i < NLAYERS*N_W4P; i += stride) {
        const int L = i >> 17, rem = i & (N_W4P - 1);
        const int c = rem >> 9, q = rem & 511;
        const int tb = c >> 5, pq = (c >> 2) & 7, kt = c & 3;
        const int l = q >> 3, e = q & 7;
        const int t = tb*4 + ((l & 15) >> 2);
        const int p = pq*4 + (l & 3);
        o4[i] = (p < PDIM)
              ? f2bf(W4[(size_t)L*N_W4 + (size_t)(t*PDIM + p)*HID + kt*32 + (l>>4)*8 + e])
              : (short)0;
    }
    for (int i = i0; i < NLAYERS*SPLIT*32; i += stride) {
        const int L = i >> 10, rem = i & 1023;
        const int t = rem >> 5, p = rem & 31;
        b4q[i] = (p < PDIM) ? b4[L*SPLIT*PDIM + t*PDIM + p] : 0.0f;
    }
}

// One coupling layer (R7 structure). ABL = additive phase-doubling probe:
// 0 = baseline; 1 = spline VALU executed twice (dup on opaque copies, sunk);
// 2 = W4 weight-load+MFMA stream executed twice (dup into sinks).
// Output is identical for all ABL values.
template<int ABL>
__global__ __launch_bounds__(NT, 4) void flow_layer(
    const float* xin, float* yout, float* logdet, const int first,
    const short* __restrict__ bW1, const float* __restrict__ b1,
    const short* __restrict__ bW2, const float* __restrict__ b2,
    const short* __restrict__ bW3, const float* __restrict__ b3,
    const short* __restrict__ bW4, const float* __restrict__ b4q,
    const int* __restrict__ mi, const int* __restrict__ ti)
{
    __shared__ short act[WAVES][32 * 64];         // 32 groups x 16 rows x 4 shorts
    __shared__ float xts[WAVES][ROWSW][33];       // spline inputs (f32)

    const int tid = threadIdx.x;
    const int wv  = tid >> 6;    // wave id
    const int l   = tid & 63;    // lane
    const int lr  = l & 15;      // row / col-in-tile
    const int lg  = l >> 4;      // 0..3
    const int rbase = blockIdx.x * MBLK + wv * ROWSW;

    short* const actw = &act[wv][0];

    // ---- gather: xm -> act groups 0..7 (bf16), xt -> xts (f32) ----
    {
        const int kcol = l & 31;
        const int mc = mi[kcol], tc = ti[kcol];
        const int r0 = l >> 5;                    // 0 or 1
        #pragma unroll
        for (int it = 0; it < 8; ++it) {
            const int r = r0 + it * 2;
            const float* row = xin + (size_t)(rbase + r) * DIM;
            const float mv = row[mc];
            actw[(kcol >> 2)*64 + r*4 + (kcol & 3)] = f2bf(mv);
            xts[wv][r][kcol] = row[tc];
            if (first) yout[(size_t)(rbase + r) * DIM + mc] = mv;  // copy-through (L0)
        }
    }

    // ================= h1 = relu(W1 @ xm^T + b1)  [K=32] =================
    {
        const bf16x8 afr = ldfrag(&actw[(2*lg)*64 + lr*4]);
        f32x4 c[8];
        #pragma unroll
        for (int nt = 0; nt < 8; ++nt) {
            const float4 bv = *reinterpret_cast<const float4*>(b1 + nt*16 + lg*4);
            c[nt] = (f32x4){bv.x, bv.y, bv.z, bv.w};
        }
        #pragma unroll
        for (int nt = 0; nt < 8; ++nt) {
            const bf16x8 wfr = *reinterpret_cast<const bf16x8*>(bW1 + (size_t)nt*512 + l*8);
            c[nt] = __builtin_amdgcn_mfma_f32_16x16x32_bf16(wfr, afr, c[nt], 0, 0, 0);
        }
        #pragma unroll
        for (int nt = 0; nt < 8; ++nt) {
            const unsigned u0 = pk2(fmaxf(c[nt][0], 0.0f), fmaxf(c[nt][1], 0.0f));
            const unsigned u1 = pk2(fmaxf(c[nt][2], 0.0f), fmaxf(c[nt][3], 0.0f));
            *reinterpret_cast<uint2*>(&actw[(nt*4 + lg)*64 + lr*4]) = (uint2){u0, u1};
        }
    }

    // ================= h2 / h3  [K=128] =================
    #pragma unroll 1
    for (int ph = 0; ph < 2; ++ph) {
        const short* Wp = ph ? bW3 : bW2;
        const float* bp = ph ? b3  : b2;
        bf16x8 afr[4];
        #pragma unroll
        for (int kt = 0; kt < 4; ++kt)
            afr[kt] = ldfrag(&actw[(kt*8 + 2*lg)*64 + lr*4]);
        f32x4 c[8];
        #pragma unroll
        for (int nt = 0; nt < 8; ++nt) {
            const float4 bv = *reinterpret_cast<const float4*>(bp + nt*16 + lg*4);
            c[nt] = (f32x4){bv.x, bv.y, bv.z, bv.w};
        }
        #pragma unroll
        for (int kt = 0; kt < 4; ++kt)
            #pragma unroll
            for (int nt = 0; nt < 8; ++nt) {
                const bf16x8 wfr = *reinterpret_cast<const bf16x8*>(Wp + (size_t)(nt*4 + kt)*512 + l*8);
                c[nt] = __builtin_amdgcn_mfma_f32_16x16x32_bf16(wfr, afr[kt], c[nt], 0, 0, 0);
            }
        #pragma unroll
        for (int nt = 0; nt < 8; ++nt) {
            const unsigned u0 = pk2(fmaxf(c[nt][0], 0.0f), fmaxf(c[nt][1], 0.0f));
            const unsigned u1 = pk2(fmaxf(c[nt][2], 0.0f), fmaxf(c[nt][3], 0.0f));
            *reinterpret_cast<uint2*>(&actw[(nt*4 + lg)*64 + lr*4]) = (uint2){u0, u1};
        }
    }

    // ================= W4 params + RQS spline =================
    bf16x8 afr[4];
    #pragma unroll
    for (int kt = 0; kt < 4; ++kt)
        afr[kt] = ldfrag(&actw[(kt*8 + 2*lg)*64 + lr*4]);

    float ldacc = 0.0f;

    #pragma unroll 1
    for (int tb = 0; tb < 8; ++tb) {
        const int t = tb*4 + lg;           // this lane's t-dim
        f32x4 c[7];
        #pragma unroll
        for (int pq = 0; pq < 7; ++pq) {
            const float4 bv = *reinterpret_cast<const float4*>(b4q + t*32 + pq*4);
            c[pq] = (f32x4){bv.x, bv.y, bv.z, bv.w};
        }
        #pragma unroll
        for (int kt = 0; kt < 4; ++kt)
            #pragma unroll
            for (int pq = 0; pq < 7; ++pq) {
                const bf16x8 wfr = *reinterpret_cast<const bf16x8*>(
                    bW4 + (size_t)((tb*8 + pq)*4 + kt)*512 + l*8);
                c[pq] = __builtin_amdgcn_mfma_f32_16x16x32_bf16(wfr, afr[kt], c[pq], 0, 0, 0);
            }

        float p[28];
        #pragma unroll
        for (int pq = 0; pq < 7; ++pq)
            #pragma unroll
            for (int j = 0; j < 4; ++j) p[pq*4 + j] = c[pq][j];

        const float x = xts[wv][lr][t];
        float dv;
        const float yv = spline_eval(p, x, dv);
        ldacc += __logf(dv);
        yout[(size_t)(rbase + lr) * DIM + ti[t]] = yv;

        // ---- ABL==1: duplicate spline on opaque copies, sink result ----
        if constexpr (ABL == 1) {
            float cc[28];
            #pragma unroll
            for (int i = 0; i < 28; ++i)
                asm("v_mov_b32 %0, %1" : "=v"(cc[i]) : "v"(p[i]));
            float x2;
            asm("v_mov_b32 %0, %1" : "=v"(x2) : "v"(x));
            float dv2;
            const float yv2 = spline_eval(cc, x2, dv2);
            asm volatile("" :: "v"(yv2), "v"(dv2));
        }
    }

    // ---- ABL==2: duplicate the whole W4 load+MFMA stream, sink results ----
    if constexpr (ABL == 2) {
        unsigned long long a = (unsigned long long)bW4;
        asm volatile("" : "+s"(a));          // opaque base: defeats CSE with real pass
        const short* w4d = (const short*)a;
        #pragma unroll 1
        for (int tb = 0; tb < 8; ++tb) {
            f32x4 cs[7];
            #pragma unroll
            for (int pq = 0; pq < 7; ++pq) cs[pq] = (f32x4){0.0f, 0.0f, 0.0f, 0.0f};
            #pragma unroll
            for (int kt = 0; kt < 4; ++kt)
                #pragma unroll
                for (int pq = 0; pq < 7; ++pq) {
                    const bf16x8 wfr = *reinterpret_cast<const bf16x8*>(
                        w4d + (size_t)((tb*8 + pq)*4 + kt)*512 + l*8);
                    cs[pq] = __builtin_amdgcn_mfma_f32_16x16x32_bf16(wfr, afr[kt], cs[pq], 0, 0, 0);
                }
            #pragma unroll
            for (int pq = 0; pq < 7; ++pq)
                asm volatile("" :: "v"(cs[pq][0]), "v"(cs[pq][1]),
                                   "v"(cs[pq][2]), "v"(cs[pq][3]));
        }
    }

    // per-row logdet: reduce over the 4 lane-groups (fixed order)
    ldacc += __shfl_xor(ldacc, 16, 64);
    ldacc += __shfl_xor(ldacc, 32, 64);
    if (l < 16) {
        const int row = rbase + lr;
        if (first) logdet[row] = ldacc;
        else       logdet[row] += ldacc;
    }
}

extern "C" void kernel_launch(void* const* d_in, const int* in_sizes, int n_in,
                              void* d_out, int out_size, void* d_ws, size_t ws_size,
                              hipStream_t stream) {
    const float* x  = (const float*)d_in[0];
    const float* W1 = (const float*)d_in[1];
    const float* b1 = (const float*)d_in[2];
    const float* W2 = (const float*)d_in[3];
    const float* b2 = (const float*)d_in[4];
    const float* W3 = (const float*)d_in[5];
    const float* b3 = (const float*)d_in[6];
    const float* W4 = (const float*)d_in[7];
    const float* b4 = (const float*)d_in[8];
    const int*   mi = (const int*)d_in[9];
    const int*   ti = (const int*)d_in[10];

    float* y      = (float*)d_out;
    float* logdet = y + (size_t)BATCH * DIM;

    short* bW1 = (short*)d_ws;
    short* bW2 = bW1 + NLAYERS * N_W1;
    short* bW3 = bW2 + NLAYERS * N_W2;
    short* bW4 = bW3 + NLAYERS * N_W2;
    float* b4q = (float*)(bW4 + (size_t)NLAYERS * N_W4P);

    cvt_weights<<<512, 256, 0, stream>>>(W1, W2, W3, W4, b4, bW1, bW2, bW3, bW4, b4q);

    dim3 grid(BATCH / MBLK), block(NT);
    for (int L = 0; L < NLAYERS; ++L) {
        const float* in = (L == 0) ? x : y;
        const int first = (L == 0) ? 1 : 0;
        const short* w1 = bW1 + (size_t)L * N_W1;
        const short* w2 = bW2 + (size_t)L * N_W2;
        const short* w3 = bW3 + (size_t)L * N_W2;
        const short* w4 = bW4 + (size_t)L * N_W4P;
        const float* bb1 = b1 + L * HID, *bb2 = b2 + L * HID, *bb3 = b3 + L * HID;
        const float* bq = b4q + (size_t)L * SPLIT * 32;
        const int* mil = mi + L * SPLIT, *til = ti + L * SPLIT;
        // Ablation map: L0,L3 baseline; L1,L4 double-spline; L2,L5 double-W4
        if (L % 3 == 0)
            flow_layer<0><<<grid, block, 0, stream>>>(in, y, logdet, first,
                w1, bb1, w2, bb2, w3, bb3, w4, bq, mil, til);
        else if (L % 3 == 1)
            flow_layer<1><<<grid, block, 0, stream>>>(in, y, logdet, first,
                w1, bb1, w2, bb2, w3, bb3, w4, bq, mil, til);
        else
            flow_layer<2><<<grid, block, 0, stream>>>(in, y, logdet, first,
                w1, bb1, w2, bb2, w3, bb3, w4, bq, mil, til);
    }
}